// Round 2
// baseline (1173.681 us; speedup 1.0000x reference)
//
#include <hip/hip_runtime.h>

// Residual_feature: three chained depthwise convs on (64,3,512,512) fp32.
//   edge     = conv(x, K1)        K1 inner 3x3 = 8*delta - m3^T m3, m3=[1,-2,1]
//   texture  = conv(edge, K2)     K2 = -(l^T l) - 2*(m^T m), l=[1,-2,2,-2,1], m=[0,1,-2,1,0]
//   residual = conv(texture, K3)  K3 = horizontal [1,-2,1]
// Per-stage zero padding == zero intermediates outside the image; implemented
// exactly via lane-boundary zeroing (wave spans the full 512-col row) and
// row-index guards.
//
// R1: occupancy was the limiter (29% occ, 32% VALUBusy, 30% HBM — latency-bound).
//     RS 32->16 doubles wave count: 6144 waves / 1536 blocks = 6 blocks/CU = 75% occ.
//     Output stores made nontemporal so the 212 MB of writes stop evicting the
//     201 MB input from the 256 MB L3 across bench iterations.
// R2: fix compile — __builtin_nontemporal_store needs a NATIVE vector type
//     (ext_vector_type), not HIP's float4 class.

#define H 512
#define W 512
#define RS 16          // output rows per wave-strip
#define STRIPS (H/RS)  // 32
#define LOG2_STRIPS 5

typedef float v4f __attribute__((ext_vector_type(4)));

__device__ __forceinline__ void load_row(const float* __restrict__ xp, int gr, int cb,
                                         int lane, float v[8], float& vl, float& vh) {
    if (gr >= 0 && gr < H) {
        const float4* p = (const float4*)(xp + gr * W + cb);
        float4 a = p[0], b = p[1];
        v[0] = a.x; v[1] = a.y; v[2] = a.z; v[3] = a.w;
        v[4] = b.x; v[5] = b.y; v[6] = b.z; v[7] = b.w;
    } else {
        #pragma unroll
        for (int j = 0; j < 8; ++j) v[j] = 0.f;
    }
    vl = __shfl_up(v[7], 1, 64);
    vh = __shfl_down(v[0], 1, 64);
    if (lane == 0)  vl = 0.f;   // x zero-pad at col -1
    if (lane == 63) vh = 0.f;   // x zero-pad at col 512
}

__global__ __launch_bounds__(256, 6)
void resid_kernel(const float* __restrict__ x, float* __restrict__ out) {
    const int lane  = threadIdx.x & 63;
    const int wid   = (blockIdx.x << 2) | (threadIdx.x >> 6);
    const int plane = wid >> LOG2_STRIPS;  // wid / STRIPS
    const int strip = wid & (STRIPS - 1);
    const int r0    = strip * RS;
    const int cb    = lane << 3;           // 8 contiguous cols per lane

    const float* __restrict__ xp = x + (size_t)plane * (H * W);
    float* __restrict__ op = out + (size_t)plane * (H * W);

    // rolling x window: rows er-1 (xa), er (xb), er+1 (xc), + L/R halo scalars
    float xa[8], xb[8], xc[8];
    float xal, xah, xbl, xbh, xcl, xch;
    // rolling windows of horizontal-filtered edge rows:
    //   L = l * edge (5-tap), M = m * edge (3-tap)
    float Lw[5][8], Mw[3][8];

    #pragma unroll
    for (int k = 0; k < 5; ++k)
        #pragma unroll
        for (int j = 0; j < 8; ++j) Lw[k][j] = 0.f;
    #pragma unroll
    for (int k = 0; k < 3; ++k)
        #pragma unroll
        for (int j = 0; j < 8; ++j) Mw[k][j] = 0.f;

    load_row(xp, r0 - 3, cb, lane, xa, xal, xah);
    load_row(xp, r0 - 2, cb, lane, xb, xbl, xbh);

    // er = edge row produced this iteration; output row p = er-2 emitted when ready
    for (int er = r0 - 2; er <= r0 + RS + 1; ++er) {
        load_row(xp, er + 1, cb, lane, xc, xcl, xch);

        float Lr[8], Mr[8];
        if (er >= 0 && er < H) {
            // ---- edge row er (K1 inner 3x3), s = x[er-1] + x[er+1]
            float s[8], e[8];
            #pragma unroll
            for (int j = 0; j < 8; ++j) s[j] = xa[j] + xc[j];
            float sl = xal + xcl, sh = xah + xch;
            #pragma unroll
            for (int j = 0; j < 8; ++j) {
                float sm = ((j == 0) ? sl  : s[j-1]) + ((j == 7) ? sh  : s[j+1]);
                float xm = ((j == 0) ? xbl : xb[j-1]) + ((j == 7) ? xbh : xb[j+1]);
                e[j] = 2.f*s[j] - sm + 2.f*xm + 4.f*xb[j];
            }
            // ---- horizontal passes: L = [1,-2,2,-2,1]*e, M = [1,-2,1]*e
            float el1 = __shfl_up(e[7], 1, 64);
            float el2 = __shfl_up(e[6], 1, 64);
            float eh1 = __shfl_down(e[0], 1, 64);
            float eh2 = __shfl_down(e[1], 1, 64);
            if (lane == 0)  { el1 = 0.f; el2 = 0.f; }   // edge==0 outside image cols
            if (lane == 63) { eh1 = 0.f; eh2 = 0.f; }
            #pragma unroll
            for (int j = 0; j < 8; ++j) {
                float em1 = (j == 0) ? el1 : e[j-1];
                float ep1 = (j == 7) ? eh1 : e[j+1];
                float em2 = (j == 0) ? el2 : ((j == 1) ? el1 : e[j-2]);
                float ep2 = (j == 7) ? eh2 : ((j == 6) ? eh1 : e[j+2]);
                float pj = em1 + ep1;
                float qj = em2 + ep2;
                Lr[j] = qj - 2.f*pj + 2.f*e[j];
                Mr[j] = pj - 2.f*e[j];
            }
        } else {
            // edge row outside image -> zero intermediate (staged padding semantics)
            #pragma unroll
            for (int j = 0; j < 8; ++j) { Lr[j] = 0.f; Mr[j] = 0.f; }
        }

        // push L (window holds rows er-4..er after push)
        #pragma unroll
        for (int j = 0; j < 8; ++j) {
            Lw[0][j] = Lw[1][j]; Lw[1][j] = Lw[2][j];
            Lw[2][j] = Lw[3][j]; Lw[3][j] = Lw[4][j];
            Lw[4][j] = Lr[j];
        }

        if (er >= r0 + 2) {
            const int orow = er - 2;
            // ---- vertical combine: texture = -(l_v . L) - 2*(m_v . M)
            // Lw[k] = L row orow-2+k ; Mw[k] (pre-push) = M row orow-1+k
            float t[8];
            #pragma unroll
            for (int j = 0; j < 8; ++j) {
                float lsum = Lw[0][j] - 2.f*Lw[1][j] + 2.f*Lw[2][j] - 2.f*Lw[3][j] + Lw[4][j];
                float msum = Mw[0][j] - 2.f*Mw[1][j] + Mw[2][j];
                t[j] = -lsum - 2.f*msum;
            }
            // ---- residual = [1,-2,1] * texture (horizontal), texture==0 outside cols
            float tl = __shfl_up(t[7], 1, 64);
            float th = __shfl_down(t[0], 1, 64);
            if (lane == 0)  tl = 0.f;
            if (lane == 63) th = 0.f;
            float r[8];
            #pragma unroll
            for (int j = 0; j < 8; ++j) {
                float rm = (j == 0) ? tl : t[j-1];
                float rp = (j == 7) ? th : t[j+1];
                r[j] = rm + rp - 2.f*t[j];
            }
            v4f o0 = { r[0], r[1], r[2], r[3] };
            v4f o1 = { r[4], r[5], r[6], r[7] };
            float* dst = op + orow * W + cb;
            __builtin_nontemporal_store(o0, (v4f*)(dst));
            __builtin_nontemporal_store(o1, (v4f*)(dst + 4));
        }

        // push M (after emit: window must lag by one row)
        #pragma unroll
        for (int j = 0; j < 8; ++j) {
            Mw[0][j] = Mw[1][j]; Mw[1][j] = Mw[2][j]; Mw[2][j] = Mr[j];
        }
        // rotate x window
        #pragma unroll
        for (int j = 0; j < 8; ++j) { xa[j] = xb[j]; xb[j] = xc[j]; }
        xal = xbl; xah = xbh; xbl = xcl; xbh = xch;
    }
}

extern "C" void kernel_launch(void* const* d_in, const int* in_sizes, int n_in,
                              void* d_out, int out_size, void* d_ws, size_t ws_size,
                              hipStream_t stream) {
    const float* x = (const float*)d_in[0];
    float* out = (float*)d_out;
    // 192 planes * 32 strips = 6144 waves / 4 waves per block = 1536 blocks (6/CU)
    resid_kernel<<<dim3(1536), dim3(256), 0, stream>>>(x, out);
}

// Round 3
// 363.964 us; speedup vs baseline: 3.2247x; 3.2247x over previous
//
#include <hip/hip_runtime.h>

// Residual_feature: three chained depthwise convs on (64,3,512,512) fp32.
//   edge     = conv(x, K1)        K1 inner 3x3 = 8*delta - m3^T m3, m3=[1,-2,1]
//   texture  = conv(edge, K2)     K2 = -(l^T l) - 2*(m^T m), l=[1,-2,2,-2,1], m=[0,1,-2,1,0]
//   residual = conv(texture, K3)  K3 = horizontal [1,-2,1]
// Per-stage zero padding == zero intermediates outside the image; implemented
// exactly via lane-boundary zeroing (wave spans the full 512-col row) and
// row-index guards.
//
// R1/R2: RS 32->16 (6144 waves / 1536 blocks = 6 blocks/CU) + nt stores.
// R2 post-mortem: __launch_bounds__(256,6) capped VGPR at ~85 -> allocator
//     spilled the rolling windows (VGPR 68->40, hbm_bytes 12x from scratch
//     spill/fill, VALUBusy 6%). dur 962us.
// R3: revert to __launch_bounds__(256,3) (known-good 68-VGPR codegen, no cap
//     pressure). Occupancy comes from the GRID: 6 blocks/CU fit in hardware at
//     68 VGPR (6 waves/SIMD x 68 = 408 <= 512). Keep RS=16 + nt stores.

#define H 512
#define W 512
#define RS 16          // output rows per wave-strip
#define STRIPS (H/RS)  // 32
#define LOG2_STRIPS 5

typedef float v4f __attribute__((ext_vector_type(4)));

__device__ __forceinline__ void load_row(const float* __restrict__ xp, int gr, int cb,
                                         int lane, float v[8], float& vl, float& vh) {
    if (gr >= 0 && gr < H) {
        const float4* p = (const float4*)(xp + gr * W + cb);
        float4 a = p[0], b = p[1];
        v[0] = a.x; v[1] = a.y; v[2] = a.z; v[3] = a.w;
        v[4] = b.x; v[5] = b.y; v[6] = b.z; v[7] = b.w;
    } else {
        #pragma unroll
        for (int j = 0; j < 8; ++j) v[j] = 0.f;
    }
    vl = __shfl_up(v[7], 1, 64);
    vh = __shfl_down(v[0], 1, 64);
    if (lane == 0)  vl = 0.f;   // x zero-pad at col -1
    if (lane == 63) vh = 0.f;   // x zero-pad at col 512
}

__global__ __launch_bounds__(256, 3)
void resid_kernel(const float* __restrict__ x, float* __restrict__ out) {
    const int lane  = threadIdx.x & 63;
    const int wid   = (blockIdx.x << 2) | (threadIdx.x >> 6);
    const int plane = wid >> LOG2_STRIPS;  // wid / STRIPS
    const int strip = wid & (STRIPS - 1);
    const int r0    = strip * RS;
    const int cb    = lane << 3;           // 8 contiguous cols per lane

    const float* __restrict__ xp = x + (size_t)plane * (H * W);
    float* __restrict__ op = out + (size_t)plane * (H * W);

    // rolling x window: rows er-1 (xa), er (xb), er+1 (xc), + L/R halo scalars
    float xa[8], xb[8], xc[8];
    float xal, xah, xbl, xbh, xcl, xch;
    // rolling windows of horizontal-filtered edge rows:
    //   L = l * edge (5-tap), M = m * edge (3-tap)
    float Lw[5][8], Mw[3][8];

    #pragma unroll
    for (int k = 0; k < 5; ++k)
        #pragma unroll
        for (int j = 0; j < 8; ++j) Lw[k][j] = 0.f;
    #pragma unroll
    for (int k = 0; k < 3; ++k)
        #pragma unroll
        for (int j = 0; j < 8; ++j) Mw[k][j] = 0.f;

    load_row(xp, r0 - 3, cb, lane, xa, xal, xah);
    load_row(xp, r0 - 2, cb, lane, xb, xbl, xbh);

    // er = edge row produced this iteration; output row p = er-2 emitted when ready
    for (int er = r0 - 2; er <= r0 + RS + 1; ++er) {
        load_row(xp, er + 1, cb, lane, xc, xcl, xch);

        float Lr[8], Mr[8];
        if (er >= 0 && er < H) {
            // ---- edge row er (K1 inner 3x3), s = x[er-1] + x[er+1]
            float s[8], e[8];
            #pragma unroll
            for (int j = 0; j < 8; ++j) s[j] = xa[j] + xc[j];
            float sl = xal + xcl, sh = xah + xch;
            #pragma unroll
            for (int j = 0; j < 8; ++j) {
                float sm = ((j == 0) ? sl  : s[j-1]) + ((j == 7) ? sh  : s[j+1]);
                float xm = ((j == 0) ? xbl : xb[j-1]) + ((j == 7) ? xbh : xb[j+1]);
                e[j] = 2.f*s[j] - sm + 2.f*xm + 4.f*xb[j];
            }
            // ---- horizontal passes: L = [1,-2,2,-2,1]*e, M = [1,-2,1]*e
            float el1 = __shfl_up(e[7], 1, 64);
            float el2 = __shfl_up(e[6], 1, 64);
            float eh1 = __shfl_down(e[0], 1, 64);
            float eh2 = __shfl_down(e[1], 1, 64);
            if (lane == 0)  { el1 = 0.f; el2 = 0.f; }   // edge==0 outside image cols
            if (lane == 63) { eh1 = 0.f; eh2 = 0.f; }
            #pragma unroll
            for (int j = 0; j < 8; ++j) {
                float em1 = (j == 0) ? el1 : e[j-1];
                float ep1 = (j == 7) ? eh1 : e[j+1];
                float em2 = (j == 0) ? el2 : ((j == 1) ? el1 : e[j-2]);
                float ep2 = (j == 7) ? eh2 : ((j == 6) ? eh1 : e[j+2]);
                float pj = em1 + ep1;
                float qj = em2 + ep2;
                Lr[j] = qj - 2.f*pj + 2.f*e[j];
                Mr[j] = pj - 2.f*e[j];
            }
        } else {
            // edge row outside image -> zero intermediate (staged padding semantics)
            #pragma unroll
            for (int j = 0; j < 8; ++j) { Lr[j] = 0.f; Mr[j] = 0.f; }
        }

        // push L (window holds rows er-4..er after push)
        #pragma unroll
        for (int j = 0; j < 8; ++j) {
            Lw[0][j] = Lw[1][j]; Lw[1][j] = Lw[2][j];
            Lw[2][j] = Lw[3][j]; Lw[3][j] = Lw[4][j];
            Lw[4][j] = Lr[j];
        }

        if (er >= r0 + 2) {
            const int orow = er - 2;
            // ---- vertical combine: texture = -(l_v . L) - 2*(m_v . M)
            // Lw[k] = L row orow-2+k ; Mw[k] (pre-push) = M row orow-1+k
            float t[8];
            #pragma unroll
            for (int j = 0; j < 8; ++j) {
                float lsum = Lw[0][j] - 2.f*Lw[1][j] + 2.f*Lw[2][j] - 2.f*Lw[3][j] + Lw[4][j];
                float msum = Mw[0][j] - 2.f*Mw[1][j] + Mw[2][j];
                t[j] = -lsum - 2.f*msum;
            }
            // ---- residual = [1,-2,1] * texture (horizontal), texture==0 outside cols
            float tl = __shfl_up(t[7], 1, 64);
            float th = __shfl_down(t[0], 1, 64);
            if (lane == 0)  tl = 0.f;
            if (lane == 63) th = 0.f;
            float r[8];
            #pragma unroll
            for (int j = 0; j < 8; ++j) {
                float rm = (j == 0) ? tl : t[j-1];
                float rp = (j == 7) ? th : t[j+1];
                r[j] = rm + rp - 2.f*t[j];
            }
            v4f o0 = { r[0], r[1], r[2], r[3] };
            v4f o1 = { r[4], r[5], r[6], r[7] };
            float* dst = op + orow * W + cb;
            __builtin_nontemporal_store(o0, (v4f*)(dst));
            __builtin_nontemporal_store(o1, (v4f*)(dst + 4));
        }

        // push M (after emit: window must lag by one row)
        #pragma unroll
        for (int j = 0; j < 8; ++j) {
            Mw[0][j] = Mw[1][j]; Mw[1][j] = Mw[2][j]; Mw[2][j] = Mr[j];
        }
        // rotate x window
        #pragma unroll
        for (int j = 0; j < 8; ++j) { xa[j] = xb[j]; xb[j] = xc[j]; }
        xal = xbl; xah = xbh; xbl = xcl; xbh = xch;
    }
}

extern "C" void kernel_launch(void* const* d_in, const int* in_sizes, int n_in,
                              void* d_out, int out_size, void* d_ws, size_t ws_size,
                              hipStream_t stream) {
    const float* x = (const float*)d_in[0];
    float* out = (float*)d_out;
    // 192 planes * 32 strips = 6144 waves / 4 waves per block = 1536 blocks (6/CU)
    resid_kernel<<<dim3(1536), dim3(256), 0, stream>>>(x, out);
}

// Round 4
// 361.631 us; speedup vs baseline: 3.2455x; 1.0065x over previous
//
#include <hip/hip_runtime.h>

// Residual_feature: three chained depthwise convs on (64,3,512,512) fp32.
//   edge     = conv(x, K1)        K1 inner 3x3 = [-1,2,-1; 2,4,2; -1,2,-1]
//   texture  = conv(edge, K2)     K2 = -(l^T l) - 2*(m^T m), l=[1,-2,2,-2,1], m=[0,1,-2,1,0]
//   residual = conv(texture, K3)  K3 = horizontal [1,-2,1]
// Staged zero padding: intermediates are zero outside the image at each stage.
//
// R3 post-mortem: occupancy pinned at ~29% (VGPR=68 -> 4 waves/SIMD cap, m69
//   bucket); per-iter dependency chain ~2960 cyc (load + 8 chained bpermutes)
//   vs ~1100 issue cyc -> latency-bound.
// R4 (this): chain surgery.
//   - vertical-first texture conv: window of 5 raw E rows (40 regs) replaces
//     Lw[5]+Mw[3] (64 regs); E built via 2 rolling accumulators (a0,a1), no
//     persistent x rows at all.
//   - x halos loaded directly (2 guarded scalar loads, same cache lines) ->
//     E production has ZERO shuffles; only output phase shuffles remain.
//   - output row p = r-4 uses only window rows from PREVIOUS iters -> current
//     load latency hides under output compute.
//   launch_bounds(256,4): VGPR cap 128, no spill risk (R2 lesson).

#define H 512
#define W 512
#define RS 16          // output rows per wave-strip
#define STRIPS (H/RS)  // 32
#define LOG2_STRIPS 5

typedef float v4f __attribute__((ext_vector_type(4)));

__global__ __launch_bounds__(256, 4)
void resid_kernel(const float* __restrict__ x, float* __restrict__ out) {
    const int lane  = threadIdx.x & 63;
    const int wid   = (blockIdx.x << 2) | (threadIdx.x >> 6);
    const int plane = wid >> LOG2_STRIPS;  // wid / STRIPS
    const int strip = wid & (STRIPS - 1);
    const int r0    = strip * RS;
    const int cb    = lane << 3;           // 8 contiguous cols per lane

    const float* __restrict__ xp = x + (size_t)plane * (H * W);
    float* __restrict__ op = out + (size_t)plane * (H * W);

    // E window: rows p-2..p+2 at output time (E0 oldest). Named arrays ->
    // all indices compile-time, no scratch risk.
    float E0[8], E1[8], E2[8], E3[8], E4[8];
    // pending vertical-K1 partial sums: a0 = E[r] so far, a1 = E[r+1] so far
    float a0[8], a1[8];
    #pragma unroll
    for (int j = 0; j < 8; ++j) {
        E0[j] = E1[j] = E2[j] = E3[j] = E4[j] = 0.f;
        a0[j] = a1[j] = 0.f;
    }

    // iter r: load x[r]; output residual row p=r-4; fold x[r] -> complete E[r-1]
    for (int r = r0 - 3; r <= r0 + RS + 3; ++r) {
        // ---- 1) issue loads for x row r (no shuffles on this chain)
        float v[8], vl, vh;
        if (r >= 0 && r < H) {
            const float4* pr = (const float4*)(xp + r * W + cb);
            float4 qa = pr[0], qb = pr[1];
            v[0] = qa.x; v[1] = qa.y; v[2] = qa.z; v[3] = qa.w;
            v[4] = qb.x; v[5] = qb.y; v[6] = qb.z; v[7] = qb.w;
            vl = (lane > 0)  ? xp[r * W + cb - 1] : 0.f;   // col cb-1
            vh = (lane < 63) ? xp[r * W + cb + 8] : 0.f;   // col cb+8
        } else {
            #pragma unroll
            for (int j = 0; j < 8; ++j) v[j] = 0.f;
            vl = 0.f; vh = 0.f;
        }

        // ---- 2) output row p = r-4 (depends ONLY on window from prev iters)
        if (r >= r0 + 4) {
            const int p = r - 4;
            float A[8], B[8];
            #pragma unroll
            for (int j = 0; j < 8; ++j) {
                // vertical taps over E rows p-2..p+2
                A[j] = E0[j] - 2.f*E1[j] + 2.f*E2[j] - 2.f*E3[j] + E4[j]; // l
                B[j] = E1[j] - 2.f*E2[j] + E3[j];                         // m
            }
            float al1 = __shfl_up(A[7], 1, 64);
            float al2 = __shfl_up(A[6], 1, 64);
            float ah1 = __shfl_down(A[0], 1, 64);
            float ah2 = __shfl_down(A[1], 1, 64);
            float bl  = __shfl_up(B[7], 1, 64);
            float bh  = __shfl_down(B[0], 1, 64);
            if (lane == 0)  { al1 = 0.f; al2 = 0.f; bl = 0.f; }  // E==0 outside cols
            if (lane == 63) { ah1 = 0.f; ah2 = 0.f; bh = 0.f; }
            float T[8];
            #pragma unroll
            for (int j = 0; j < 8; ++j) {
                float am2 = (j >= 2) ? A[j-2] : ((j == 1) ? al1 : al2);
                float am1 = (j >= 1) ? A[j-1] : al1;
                float ap1 = (j <= 6) ? A[j+1] : ah1;
                float ap2 = (j <= 5) ? A[j+2] : ((j == 6) ? ah1 : ah2);
                float bm  = (j >= 1) ? B[j-1] : bl;
                float bp  = (j <= 6) ? B[j+1] : bh;
                float lt = am2 - 2.f*am1 + 2.f*A[j] - 2.f*ap1 + ap2;
                float mt = bm - 2.f*B[j] + bp;
                T[j] = -lt - 2.f*mt;
            }
            float tl = __shfl_up(T[7], 1, 64);
            float th = __shfl_down(T[0], 1, 64);
            if (lane == 0)  tl = 0.f;   // texture==0 outside cols
            if (lane == 63) th = 0.f;
            float R[8];
            #pragma unroll
            for (int j = 0; j < 8; ++j) {
                float tm = (j >= 1) ? T[j-1] : tl;
                float tp = (j <= 6) ? T[j+1] : th;
                R[j] = tm - 2.f*T[j] + tp;
            }
            v4f o0 = { R[0], R[1], R[2], R[3] };
            v4f o1 = { R[4], R[5], R[6], R[7] };
            float* dst = op + p * W + cb;
            __builtin_nontemporal_store(o0, (v4f*)(dst));
            __builtin_nontemporal_store(o1, (v4f*)(dst + 4));
        }

        // ---- 3) fold x row r: h1 = [-1,2,-1]*x (outer K1 rows), h2 = [2,4,2]*x
        // E[p] = h1(x[p-1]) + h2(x[p]) + h1(x[p+1]); completes E[r-1] now.
        const bool ein = (r - 1 >= 0) && (r - 1 < H);  // staged padding: E=0 outside
        #pragma unroll
        for (int j = 0; j < 8; ++j) {
            float xm = (j >= 1) ? v[j-1] : vl;
            float xq = (j <= 6) ? v[j+1] : vh;
            float h1 = 2.f*v[j] - xm - xq;
            float h2 = 8.f*v[j] - 2.f*h1;
            float En = ein ? (a0[j] + h1) : 0.f;
            a0[j] = a1[j] + h2;
            a1[j] = h1;
            E0[j] = E1[j]; E1[j] = E2[j]; E2[j] = E3[j]; E3[j] = E4[j]; E4[j] = En;
        }
    }
}

extern "C" void kernel_launch(void* const* d_in, const int* in_sizes, int n_in,
                              void* d_out, int out_size, void* d_ws, size_t ws_size,
                              hipStream_t stream) {
    const float* x = (const float*)d_in[0];
    float* out = (float*)d_out;
    // 192 planes * 32 strips = 6144 waves / 4 waves per block = 1536 blocks
    resid_kernel<<<dim3(1536), dim3(256), 0, stream>>>(x, out);
}